// Round 1
// baseline (209.668 us; speedup 1.0000x reference)
//
#include <hip/hip_runtime.h>

constexpr int B = 2, CH = 128, OUTC = 128, Hh = 64, Ww = 64;
constexpr int COMP = 64, K2 = 25, QQ = 100;   // K2*S*S

// ---------------- Kernel 1: 1x1 channel compressor ----------------
// compressed[b, o, hw] = sum_c w[o,c] * x[b,c,hw] + bias[o]
__global__ void k_compress(const float* __restrict__ x, const float* __restrict__ w,
                           const float* __restrict__ bias, float* __restrict__ out) {
    int bid = blockIdx.x;
    int b   = bid >> 7;        // /128
    int rem = bid & 127;
    int og  = rem >> 4;        // 0..7  (8 output channels each)
    int hwb = rem & 15;
    int hw  = hwb * 256 + threadIdx.x;
    float acc[8];
#pragma unroll
    for (int k = 0; k < 8; ++k) acc[k] = 0.f;
    const float* xb = x + (b * CH) * 4096 + hw;
#pragma unroll 4
    for (int c = 0; c < CH; ++c) {
        float xv = xb[c * 4096];
#pragma unroll
        for (int k = 0; k < 8; ++k) acc[k] += w[(og * 8 + k) * CH + c] * xv;
    }
#pragma unroll
    for (int k = 0; k < 8; ++k)
        out[((b * COMP + og * 8 + k) << 12) + hw] = acc[k] + bias[og * 8 + k];
}

// ---------------- Kernel 2: 3x3 content encoder ----------------
// enc[b,q,h,w] = sum_{c,di,dj} comp[b,c,h+di-1,w+dj-1]*w[q,c,di,dj] + bias[q]
__global__ void k_encoder(const float* __restrict__ comp, const float* __restrict__ w,
                          const float* __restrict__ bias, float* __restrict__ enc) {
    __shared__ float cs[16 * 18 * 18];   // 16 channels x 18x18 halo tile
    int bid  = blockIdx.x;
    int b    = bid / 160;
    int rem  = bid % 160;
    int qb   = rem >> 4;                 // 0..9 (10 q's each)
    int tile = rem & 15;
    int ty = tile >> 2, tx = tile & 3;
    int y = threadIdx.x >> 4, xcol = threadIdx.x & 15;
    float acc[10];
#pragma unroll
    for (int q = 0; q < 10; ++q) acc[q] = 0.f;
    for (int ch = 0; ch < 4; ++ch) {
        __syncthreads();
        for (int idx = threadIdx.x; idx < 5184; idx += 256) {
            int cc = idx / 324;
            int r2 = idx - cc * 324;
            int yy = r2 / 18;
            int xx = r2 - yy * 18;
            int gr = ty * 16 - 1 + yy;
            int gc = tx * 16 - 1 + xx;
            float v = 0.f;
            if ((unsigned)gr < 64u && (unsigned)gc < 64u)
                v = comp[((b * COMP + ch * 16 + cc) << 12) + (gr << 6) + gc];
            cs[idx] = v;
        }
        __syncthreads();
#pragma unroll 2
        for (int cc = 0; cc < 16; ++cc) {
            float xv[9];
#pragma unroll
            for (int di = 0; di < 3; ++di)
#pragma unroll
                for (int dj = 0; dj < 3; ++dj)
                    xv[di * 3 + dj] = cs[cc * 324 + (y + di) * 18 + (xcol + dj)];
#pragma unroll
            for (int q = 0; q < 10; ++q) {
                const float* wq = w + ((qb * 10 + q) * COMP + ch * 16 + cc) * 9;
#pragma unroll
                for (int t = 0; t < 9; ++t) acc[q] += wq[t] * xv[t];
            }
        }
    }
#pragma unroll
    for (int q = 0; q < 10; ++q)
        enc[((b * QQ + qb * 10 + q) << 12) + ((ty * 16 + y) << 6) + (tx * 16 + xcol)]
            = acc[q] + bias[qb * 10 + q];
}

// ---------------- Kernel 3: fused softmax + reassembly + projection ----------------
// Tile: 4 (hs) x 16 (ws) output pixels per block; 512 blocks total.
__global__ void k_reassemble(const float* __restrict__ x, const float* __restrict__ enc,
                             const float* __restrict__ wproj, const float* __restrict__ bproj,
                             float* __restrict__ out) {
    __shared__ float buf0[9216];  // xs [128][6][12] (pitch 72); later wp [128][65]
    __shared__ float sm[1600];    // [25][64] logits -> softmax weights
    __shared__ float re[8192];    // reassembled [128][64]
    int bid = blockIdx.x;
    int b   = bid >> 8;
    int rem = bid & 255;
    int ty  = rem >> 3;   // 0..31 -> hs base = ty*4
    int tx  = rem & 7;    // 0..7  -> ws base = tx*16
    int tid = threadIdx.x;

    // stage x halo: low-res rows ty*2-2 .. +3 (6), cols tx*8-2 .. +9 (12), all 128 ch
    {
        int R0 = ty * 2 - 2, C0 = tx * 8 - 2;
        for (int idx = tid; idx < 9216; idx += 256) {
            int c  = idx / 72;
            int r2 = idx - c * 72;
            int yy = r2 / 12;
            int xx = r2 - yy * 12;
            int gr = R0 + yy, gc = C0 + xx;
            float v = 0.f;
            if ((unsigned)gr < 64u && (unsigned)gc < 64u)
                v = x[((b * CH + c) << 12) + (gr << 6) + gc];
            buf0[idx] = v;
        }
        // stage 25 logits per pixel (pixel-shuffled indexing into enc)
        for (int idx = tid; idx < 1600; idx += 256) {
            int k  = idx >> 6;
            int p  = idx & 63;
            int py = p >> 4, px = p & 15;
            int q  = k * 4 + (py & 1) * 2 + (px & 1);
            int h0 = ty * 2 + (py >> 1);
            int w0 = tx * 8 + (px >> 1);
            sm[idx] = enc[((b * QQ + q) << 12) + (h0 << 6) + w0];
        }
    }
    __syncthreads();
    // softmax over 25 positions, one pixel per lane (wave 0)
    if (tid < 64) {
        float v[25];
#pragma unroll
        for (int k = 0; k < 25; ++k) v[k] = sm[k * 64 + tid];
        float m = v[0];
#pragma unroll
        for (int k = 1; k < 25; ++k) m = fmaxf(m, v[k]);
        float s = 0.f;
#pragma unroll
        for (int k = 0; k < 25; ++k) { v[k] = __expf(v[k] - m); s += v[k]; }
        float inv = 1.f / s;
#pragma unroll
        for (int k = 0; k < 25; ++k) sm[k * 64 + tid] = v[k] * inv;
    }
    __syncthreads();
    // reassembly: re[c][p] = sum_{i,j} wk[i*5+j][p] * xs[c][(py>>1)+i][(px>>1)+j]
    {
        int p  = tid & 63;
        int cg = tid >> 6;
        int py = p >> 4, px = p & 15;
        int ry = py >> 1, rx = px >> 1;
        float wk[25];
#pragma unroll
        for (int k = 0; k < 25; ++k) wk[k] = sm[k * 64 + p];
        for (int k = 0; k < 32; ++k) {
            int c = cg * 32 + k;
            const float* xsc = buf0 + c * 72 + ry * 12 + rx;
            float acc = 0.f;
#pragma unroll
            for (int i = 0; i < 5; ++i)
#pragma unroll
                for (int j = 0; j < 5; ++j)
                    acc += wk[i * 5 + j] * xsc[i * 12 + j];
            re[c * 64 + p] = acc;
        }
    }
    // projection: out[o][p] = sum_c wp[o][c] * re[c][p] + b[o]
    int to = tid & 63, tp = tid >> 6;     // o pair = (2to, 2to+1); row tp, 16 cols
    float acc0[16], acc1[16];
#pragma unroll
    for (int u = 0; u < 16; ++u) { acc0[u] = 0.f; acc1[u] = 0.f; }
    for (int chalf = 0; chalf < 2; ++chalf) {
        __syncthreads();  // prior buf0 readers done / re visible
        for (int idx = tid; idx < 8192; idx += 256) {
            int o = idx >> 6, c = idx & 63;
            buf0[o * 65 + c] = wproj[(o << 7) + chalf * 64 + c];   // pitch 65: no bank conflict
        }
        __syncthreads();
#pragma unroll 4
        for (int c = 0; c < 64; ++c) {
            float w0v = buf0[(2 * to) * 65 + c];
            float w1v = buf0[(2 * to + 1) * 65 + c];
            const float* rc = re + (chalf * 64 + c) * 64 + tp * 16;
#pragma unroll
            for (int u = 0; u < 16; ++u) {
                float rv = rc[u];
                acc0[u] += w0v * rv;
                acc1[u] += w1v * rv;
            }
        }
    }
    // store: 2 output channels x 16 consecutive ws, float4-vectorized
    int hs = ty * 4 + tp;
    int wsb = tx * 16;
    int o0 = 2 * to, o1 = 2 * to + 1;
    float b0 = bproj[o0], b1 = bproj[o1];
    float* p0 = out + ((b * OUTC + o0) << 14) + (hs << 7) + wsb;
    float* p1 = out + ((b * OUTC + o1) << 14) + (hs << 7) + wsb;
#pragma unroll
    for (int u4 = 0; u4 < 4; ++u4) {
        float4 v0 = make_float4(acc0[u4 * 4 + 0] + b0, acc0[u4 * 4 + 1] + b0,
                                acc0[u4 * 4 + 2] + b0, acc0[u4 * 4 + 3] + b0);
        float4 v1 = make_float4(acc1[u4 * 4 + 0] + b1, acc1[u4 * 4 + 1] + b1,
                                acc1[u4 * 4 + 2] + b1, acc1[u4 * 4 + 3] + b1);
        *(float4*)(p0 + u4 * 4) = v0;
        *(float4*)(p1 + u4 * 4) = v1;
    }
}

extern "C" void kernel_launch(void* const* d_in, const int* in_sizes, int n_in,
                              void* d_out, int out_size, void* d_ws, size_t ws_size,
                              hipStream_t stream) {
    const float* x      = (const float*)d_in[0];
    const float* w_comp = (const float*)d_in[1];
    const float* b_comp = (const float*)d_in[2];
    const float* w_enc  = (const float*)d_in[3];
    const float* b_enc  = (const float*)d_in[4];
    const float* w_proj = (const float*)d_in[5];
    const float* b_proj = (const float*)d_in[6];
    float* out  = (float*)d_out;
    float* comp = (float*)d_ws;                     // 2*64*4096 floats = 2 MB
    float* enc  = comp + B * COMP * 4096;           // 2*100*4096 floats = 3.125 MB

    k_compress<<<256, 256, 0, stream>>>(x, w_comp, b_comp, comp);
    k_encoder<<<320, 256, 0, stream>>>(comp, w_enc, b_enc, enc);
    k_reassemble<<<512, 256, 0, stream>>>(x, enc, w_proj, b_proj, out);
}

// Round 2
// 172.614 us; speedup vs baseline: 1.2147x; 1.2147x over previous
//
#include <hip/hip_runtime.h>

constexpr int B = 2, CH = 128, OUTC = 128;
constexpr int COMP = 64, QQ = 100;

// ---------------- Kernel 1: 1x1 channel compressor (c-split 4-way) ----------------
// grid = b(2) x og(8) x hwchunk(64) = 1024 blocks, 256 threads
__global__ __launch_bounds__(256, 4)
void k_compress(const float* __restrict__ x, const float* __restrict__ w,
                const float* __restrict__ bias, float* __restrict__ out) {
    __shared__ float red[8 * 256];
    int bid = blockIdx.x;
    int b   = bid >> 9;
    int rem = bid & 511;
    int og  = rem >> 6;        // 0..7 -> 8 output channels
    int hwb = rem & 63;        // 64-pixel chunk
    int tid = threadIdx.x;
    int px  = tid & 63;
    int cs4 = tid >> 6;        // c-split 0..3
    int hw  = hwb * 64 + px;

    float acc[8];
#pragma unroll
    for (int k = 0; k < 8; ++k) acc[k] = 0.f;
    const float* xb = x + ((b * CH + cs4 * 32) << 12) + hw;
    const float* wb = w + (og * 8) * CH + cs4 * 32;
#pragma unroll 8
    for (int c = 0; c < 32; ++c) {
        float xv = xb[c << 12];
#pragma unroll
        for (int k = 0; k < 8; ++k) acc[k] += wb[k * CH + c] * xv;
    }
#pragma unroll
    for (int k = 0; k < 8; ++k) red[k * 256 + tid] = acc[k];
    __syncthreads();
#pragma unroll
    for (int kk = 0; kk < 2; ++kk) {
        int k = (tid >> 6) + kk * 4;
        float s = red[k * 256 + px] + red[k * 256 + px + 64]
                + red[k * 256 + px + 128] + red[k * 256 + px + 192];
        out[((b * COMP + og * 8 + k) << 12) + hw] = s + bias[og * 8 + k];
    }
}

// ---------------- Kernel 2: 3x3 content encoder ----------------
// grid = b(2) x qg(20, 5 q's each) x tile(16, 16x16) = 640 blocks
__global__ __launch_bounds__(256, 5)
void k_encoder(const float* __restrict__ comp, const float* __restrict__ w,
               const float* __restrict__ bias, float* __restrict__ enc) {
    __shared__ float cs[16 * 18 * 24];   // 16 ch x 18 rows x pitch 24 (exact 2-way banks)
    int bid  = blockIdx.x;
    int b    = bid / 320;
    int rem  = bid % 320;
    int qg   = rem >> 4;                 // 0..19
    int tile = rem & 15;
    int ty = tile >> 2, tx = tile & 3;
    int tid = threadIdx.x;
    int y = tid >> 4, xcol = tid & 15;

    float acc[5];
#pragma unroll
    for (int q = 0; q < 5; ++q) acc[q] = 0.f;

    for (int chg = 0; chg < 4; ++chg) {
        __syncthreads();
        for (int idx = tid; idx < 5184; idx += 256) {
            int cc = idx / 324;
            int r2 = idx - cc * 324;
            int yy = r2 / 18;
            int xx = r2 - yy * 18;
            int gr = ty * 16 - 1 + yy;
            int gc = tx * 16 - 1 + xx;
            float v = 0.f;
            if ((unsigned)gr < 64u && (unsigned)gc < 64u)
                v = comp[((b * COMP + chg * 16 + cc) << 12) + (gr << 6) + gc];
            cs[cc * 432 + yy * 24 + xx] = v;
        }
        __syncthreads();
#pragma unroll 4
        for (int cc = 0; cc < 16; ++cc) {
            float xv[9];
            const float* tb = cs + cc * 432 + y * 24 + xcol;
#pragma unroll
            for (int di = 0; di < 3; ++di)
#pragma unroll
                for (int dj = 0; dj < 3; ++dj)
                    xv[di * 3 + dj] = tb[di * 24 + dj];
            const float* wq = w + ((qg * 5) * COMP + chg * 16 + cc) * 9;
#pragma unroll
            for (int q = 0; q < 5; ++q)
#pragma unroll
                for (int t = 0; t < 9; ++t)
                    acc[q] += wq[q * COMP * 9 + t] * xv[t];
        }
    }
#pragma unroll
    for (int q = 0; q < 5; ++q)
        enc[((b * QQ + qg * 5 + q) << 12) + ((ty * 16 + y) << 6) + (tx * 16 + xcol)]
            = acc[q] + bias[qg * 5 + q];
}

// ---------------- Kernel 3: fused softmax + reassembly + projection ----------------
// Tile: 4 (hs) x 16 (ws) output pixels per block; grid = 2 x 32 x 8 = 512 blocks.
// re buffer XOR-swizzle: index p stored at p ^ RESW(c) to avoid cgrp bank aliasing.
#define RESW(c) (((((c) >> 3) & 3)) << 3)

__global__ __launch_bounds__(256, 2)
void k_reassemble(const float* __restrict__ x, const float* __restrict__ enc,
                  const float* __restrict__ wproj, const float* __restrict__ bproj,
                  float* __restrict__ out) {
    __shared__ float buf0[9344];  // xs: [128 c][6 rows][12 cols], c-stride 73; later wt [64][128]
    __shared__ float sm[1600];    // [25 k][16 lowpx][4 subpx]
    __shared__ float re[8192];    // reassembled [128 c][64 p] (XOR-swizzled)
    int bid = blockIdx.x;
    int b   = bid >> 8;
    int rem = bid & 255;
    int ty  = rem >> 3;   // hs base = ty*4  (h0 base = ty*2)
    int tx  = rem & 7;    // ws base = tx*16 (w0 base = tx*8)
    int tid = threadIdx.x;

    // ---- stage x halo: low-res rows ty*2-2..+3 (6), cols tx*8-2..+9 (12), 128 ch
    {
        int R0 = ty * 2 - 2, C0 = tx * 8 - 2;
        for (int idx = tid; idx < 9216; idx += 256) {
            int c  = idx / 72;
            int r2 = idx - c * 72;
            int yy = r2 / 12;
            int xx = r2 - yy * 12;
            int gr = R0 + yy, gc = C0 + xx;
            float v = 0.f;
            if ((unsigned)gr < 64u && (unsigned)gc < 64u)
                v = x[((b * CH + c) << 12) + (gr << 6) + gc];
            buf0[c * 73 + yy * 12 + xx] = v;
        }
        // ---- stage 100 logit planes -> sm[k][lowpx][subpx]
        for (int idx = tid; idx < 1600; idx += 256) {
            int q     = idx >> 4;        // 0..99
            int lowpx = idx & 15;
            int h0 = ty * 2 + (lowpx >> 3);
            int w0 = tx * 8 + (lowpx & 7);
            sm[(q >> 2) * 64 + lowpx * 4 + (q & 3)]
                = enc[((b * QQ + q) << 12) + (h0 << 6) + w0];
        }
    }
    __syncthreads();
    // ---- softmax over 25 k (one pixel per lane of wave 0)
    if (tid < 64) {
        float v[25];
#pragma unroll
        for (int k = 0; k < 25; ++k) v[k] = sm[k * 64 + tid];
        float m = v[0];
#pragma unroll
        for (int k = 1; k < 25; ++k) m = fmaxf(m, v[k]);
        float s = 0.f;
#pragma unroll
        for (int k = 0; k < 25; ++k) { v[k] = __expf(v[k] - m); s += v[k]; }
        float inv = 1.f / s;
#pragma unroll
        for (int k = 0; k < 25; ++k) sm[k * 64 + tid] = v[k] * inv;
    }
    __syncthreads();
    // ---- reassembly: thread owns (lowpx, 8 channels), computes 4 subpixels
    {
        int lowpx = tid & 15;
        int cgrp  = tid >> 4;          // 0..15 -> c = cgrp*8 + cc
        int ly = lowpx >> 3, lx = lowpx & 7;
        float acc[8][4];
#pragma unroll
        for (int cc = 0; cc < 8; ++cc)
#pragma unroll
            for (int s = 0; s < 4; ++s) acc[cc][s] = 0.f;
#pragma unroll
        for (int k = 0; k < 25; ++k) {
            int i = k / 5, j = k % 5;
            float4 wk4 = *(const float4*)&sm[k * 64 + lowpx * 4];
            const float* tb = buf0 + (cgrp * 8) * 73 + (ly + i) * 12 + (lx + j);
#pragma unroll
            for (int cc = 0; cc < 8; ++cc) {
                float tap = tb[cc * 73];
                acc[cc][0] += wk4.x * tap;
                acc[cc][1] += wk4.y * tap;
                acc[cc][2] += wk4.z * tap;
                acc[cc][3] += wk4.w * tap;
            }
        }
        int p0 = (ly * 2) * 16 + lx * 2;   // subpx (0,0); s=1 -> +1; s=2 -> +16; s=3 -> +17
#pragma unroll
        for (int cc = 0; cc < 8; ++cc) {
            int c = cgrp * 8 + cc;
            int sw = RESW(c);
            *(float2*)&re[c * 64 + (p0 ^ sw)]        = make_float2(acc[cc][0], acc[cc][1]);
            *(float2*)&re[c * 64 + ((p0 + 16) ^ sw)] = make_float2(acc[cc][2], acc[cc][3]);
        }
    }
    // ---- projection: thread owns (8 o, 4 px); wt staged transposed per c-half
    int og = tid >> 4;       // 0..15 -> o = og*8..+7
    int pg = tid & 15;       // px = pg*4..+3 (logical)
    float accp[8][4];
#pragma unroll
    for (int oo = 0; oo < 8; ++oo)
#pragma unroll
        for (int u = 0; u < 4; ++u) accp[oo][u] = 0.f;
    for (int ch = 0; ch < 2; ++ch) {
        __syncthreads();   // re complete / prior wt readers done
        for (int idx = tid; idx < 8192; idx += 256) {
            int o = idx & 127;
            int c = idx >> 7;       // 0..63
            buf0[c * 128 + o] = wproj[(o << 7) + ch * 64 + c];
        }
        __syncthreads();
#pragma unroll 2
        for (int c = 0; c < 64; ++c) {
            int gc = ch * 64 + c;
            float4 rv = *(const float4*)&re[gc * 64 + ((pg * 4) ^ RESW(gc))];
            float4 wa = *(const float4*)&buf0[c * 128 + og * 8];
            float4 wb = *(const float4*)&buf0[c * 128 + og * 8 + 4];
            float wv[8] = {wa.x, wa.y, wa.z, wa.w, wb.x, wb.y, wb.z, wb.w};
            float rvv[4] = {rv.x, rv.y, rv.z, rv.w};
#pragma unroll
            for (int oo = 0; oo < 8; ++oo)
#pragma unroll
                for (int u = 0; u < 4; ++u) accp[oo][u] += wv[oo] * rvv[u];
        }
    }
    // ---- store: 8 o x 4 consecutive ws per thread
    int hs  = ty * 4 + (pg >> 2);
    int wsb = tx * 16 + (pg & 3) * 4;
#pragma unroll
    for (int oo = 0; oo < 8; ++oo) {
        int o = og * 8 + oo;
        float bo = bproj[o];
        float4 v = make_float4(accp[oo][0] + bo, accp[oo][1] + bo,
                               accp[oo][2] + bo, accp[oo][3] + bo);
        *(float4*)(out + ((b * OUTC + o) << 14) + (hs << 7) + wsb) = v;
    }
}

extern "C" void kernel_launch(void* const* d_in, const int* in_sizes, int n_in,
                              void* d_out, int out_size, void* d_ws, size_t ws_size,
                              hipStream_t stream) {
    const float* x      = (const float*)d_in[0];
    const float* w_comp = (const float*)d_in[1];
    const float* b_comp = (const float*)d_in[2];
    const float* w_enc  = (const float*)d_in[3];
    const float* b_enc  = (const float*)d_in[4];
    const float* w_proj = (const float*)d_in[5];
    const float* b_proj = (const float*)d_in[6];
    float* out  = (float*)d_out;
    float* comp = (float*)d_ws;                     // 2*64*4096 floats
    float* enc  = comp + B * COMP * 4096;           // 2*100*4096 floats

    k_compress<<<1024, 256, 0, stream>>>(x, w_comp, b_comp, comp);
    k_encoder<<<640, 256, 0, stream>>>(comp, w_enc, b_enc, enc);
    k_reassemble<<<512, 256, 0, stream>>>(x, enc, w_proj, b_proj, out);
}

// Round 3
// 142.800 us; speedup vs baseline: 1.4683x; 1.2088x over previous
//
#include <hip/hip_runtime.h>

constexpr int B = 2, CH = 128, OUTC = 128;
constexpr int QQ = 100;

using short8 = __attribute__((ext_vector_type(8))) short;
using f32x4  = __attribute__((ext_vector_type(4))) float;

__device__ inline unsigned short f2bf(float f) {
    unsigned u = __float_as_uint(f);
    return (unsigned short)((u + 0x7FFF + ((u >> 16) & 1)) >> 16);
}

// ---------------- K0: x (f32 [b][c][y][x]) -> xt (bf16 [b][px][c]) ----------------
// grid = 2 b x 64 y x 2 chalf = 256 blocks, 128 thr
__global__ __launch_bounds__(128)
void k_x2bf(const float* __restrict__ x, unsigned short* __restrict__ xt) {
    __shared__ unsigned short t[64 * 72];   // [px 64][c_local 64 + pad], pitch 144B (16B-aligned)
    int blk = blockIdx.x;
    int b = blk >> 7;
    int y = (blk >> 1) & 63;
    int chalf = blk & 1;
    int tid = threadIdx.x;
    int lx = tid & 63, ch2 = tid >> 6;
    const float* xb = x + (b * CH + chalf * 64 + ch2 * 32) * 4096 + y * 64 + lx;
#pragma unroll 8
    for (int c = 0; c < 32; ++c)
        t[lx * 72 + ch2 * 32 + c] = f2bf(xb[c * 4096]);
    __syncthreads();
    int px = tid >> 1, h = tid & 1;
    unsigned short* dst = xt + (b * 4096 + y * 64 + px) * 128 + chalf * 64 + h * 32;
    const unsigned short* srcp = t + px * 72 + h * 32;
#pragma unroll
    for (int j = 0; j < 4; ++j)
        *(short8*)(dst + j * 8) = *(const short8*)(srcp + j * 8);
}

// ---------------- KW: fold compress into encoder weights ----------------
// Weff[q(128 pad)][kap 9][c 128] bf16 = sum_m we[q][m][kap] * wc[m][c]; block 576 does beff.
__global__ __launch_bounds__(256)
void k_wfold(const float* __restrict__ we, const float* __restrict__ wc,
             const float* __restrict__ be, const float* __restrict__ bc,
             unsigned short* __restrict__ weff, float* __restrict__ beff) {
    int blk = blockIdx.x;
    if (blk == 576) {
        int q = threadIdx.x;
        if (q < 128) {
            float s = 0.f;
            if (q < QQ) {
                s = be[q];
                for (int m = 0; m < 64; ++m) {
                    float t = 0.f;
#pragma unroll
                    for (int k = 0; k < 9; ++k) t += we[(q * 64 + m) * 9 + k];
                    s += t * bc[m];   // b_comp fold-through (zero in practice)
                }
            }
            beff[q] = s;
        }
        return;
    }
    int gid = blk * 256 + threadIdx.x;      // < 147456 = 128*1152
    int q = gid / 1152;
    int r = gid - q * 1152;
    int kap = r >> 7, c = r & 127;
    float acc = 0.f;
    if (q < QQ) {
        const float* wep = we + (q * 64) * 9 + kap;
        const float* wcp = wc + c;
#pragma unroll 8
        for (int m = 0; m < 64; ++m)
            acc += wep[m * 9] * wcp[m * 128];
    }
    weff[gid] = f2bf(acc);
}

// ---------------- KE: encoder as MFMA GEMM, K split 3-way over kappa ----------------
// grid = 3 ks x 2 b x 64 tiles(8x8 px) = 384 blocks, 512 thr (8 waves).
// Partials P[ks][b][q 128][4096] f32 (reduced + bias'd in k_reassemble staging).
__global__ __launch_bounds__(512, 2)
void k_encmfma(const unsigned short* __restrict__ xt, const unsigned short* __restrict__ weff,
               float* __restrict__ P) {
    __shared__ unsigned short xhs[100 * 136];   // halo 10x10 px x 128c, pitch 272B
    __shared__ unsigned short Wl[128 * 136];    // 128 q x 128 c (one kappa), pitch 272B
    int blk = blockIdx.x;
    int ks = blk >> 7;              // 0..2
    int rem = blk & 127;
    int b = rem >> 6;
    int tile = rem & 63;
    int y0 = (tile >> 3) * 8, x0 = (tile & 7) * 8;
    int tid = threadIdx.x;

    // stage x halo (zeros outside)
    for (int idx = tid; idx < 800; idx += 512) {
        int hp = idx >> 3, cq = idx & 7;
        int hy = hp / 10, hx = hp - hy * 10;
        int gy = y0 - 1 + hy, gx = x0 - 1 + hx;
        short8 v0 = {0, 0, 0, 0, 0, 0, 0, 0}, v1 = {0, 0, 0, 0, 0, 0, 0, 0};
        if ((unsigned)gy < 64u && (unsigned)gx < 64u) {
            const unsigned short* src = xt + (b * 4096 + gy * 64 + gx) * 128 + cq * 16;
            v0 = *(const short8*)src;
            v1 = *(const short8*)(src + 8);
        }
        *(short8*)&xhs[hp * 136 + cq * 16] = v0;
        *(short8*)&xhs[hp * 136 + cq * 16 + 8] = v1;
    }

    int lane = tid & 63, w = tid >> 6;
    int Nf = w & 3, Mhalf = w >> 2;
    int kgrp = lane >> 4, l15 = lane & 15;
    int n = Nf * 16 + l15;
    int py = n >> 3, pxx = n & 7;

    f32x4 acc[4];
#pragma unroll
    for (int mm = 0; mm < 4; ++mm) acc[mm] = f32x4{0.f, 0.f, 0.f, 0.f};

    for (int kk = 0; kk < 3; ++kk) {
        int kap = ks * 3 + kk;
        __syncthreads();
        for (int idx = tid; idx < 1024; idx += 512) {
            int q = idx >> 3, cq = idx & 7;
            const unsigned short* src = weff + (q * 9 + kap) * 128 + cq * 16;
            *(short8*)&Wl[q * 136 + cq * 16]     = *(const short8*)src;
            *(short8*)&Wl[q * 136 + cq * 16 + 8] = *(const short8*)(src + 8);
        }
        __syncthreads();
        int dy = kap / 3, dx = kap - dy * 3;
        int hp = (py + dy) * 10 + (pxx + dx);
#pragma unroll
        for (int kstep = 0; kstep < 4; ++kstep) {
            short8 bfrag = *(const short8*)&xhs[hp * 136 + kstep * 32 + kgrp * 8];
#pragma unroll
            for (int mm = 0; mm < 4; ++mm) {
                int q = (Mhalf * 4 + mm) * 16 + l15;
                short8 afrag = *(const short8*)&Wl[q * 136 + kstep * 32 + kgrp * 8];
                acc[mm] = __builtin_amdgcn_mfma_f32_16x16x32_bf16(afrag, bfrag, acc[mm], 0, 0, 0);
            }
        }
    }
    int gpx = (y0 + py) * 64 + (x0 + pxx);
    float* Pb = P + ((ks * 2 + b) * 128) * 4096 + gpx;
#pragma unroll
    for (int mm = 0; mm < 4; ++mm) {
        int qbase = (Mhalf * 4 + mm) * 16 + kgrp * 4;
#pragma unroll
        for (int rg = 0; rg < 4; ++rg)
            Pb[(qbase + rg) * 4096] = acc[mm][rg];
    }
}

// ---------------- Kernel 3: fused softmax + reassembly + projection ----------------
// (round-2 proven kernel; only sm staging changed to reduce 3 K-split partials + bias)
#define RESW(c) (((((c) >> 3) & 3)) << 3)

__global__ __launch_bounds__(256, 2)
void k_reassemble(const float* __restrict__ x, const float* __restrict__ P,
                  const float* __restrict__ beff,
                  const float* __restrict__ wproj, const float* __restrict__ bproj,
                  float* __restrict__ out) {
    __shared__ float buf0[9344];  // xs: [128 c][6 rows][12 cols], c-stride 73; later wt [64][128]
    __shared__ float sm[1600];    // [25 k][16 lowpx][4 subpx]
    __shared__ float re[8192];    // reassembled [128 c][64 p] (XOR-swizzled)
    int bid = blockIdx.x;
    int b   = bid >> 8;
    int rem = bid & 255;
    int ty  = rem >> 3;   // hs base = ty*4  (h0 base = ty*2)
    int tx  = rem & 7;    // ws base = tx*16 (w0 base = tx*8)
    int tid = threadIdx.x;

    {
        int R0 = ty * 2 - 2, C0 = tx * 8 - 2;
        for (int idx = tid; idx < 9216; idx += 256) {
            int c  = idx / 72;
            int r2 = idx - c * 72;
            int yy = r2 / 12;
            int xx = r2 - yy * 12;
            int gr = R0 + yy, gc = C0 + xx;
            float v = 0.f;
            if ((unsigned)gr < 64u && (unsigned)gc < 64u)
                v = x[((b * CH + c) << 12) + (gr << 6) + gc];
            buf0[c * 73 + yy * 12 + xx] = v;
        }
        // stage 100 logit planes: reduce 3 K-split partials + bias
        for (int idx = tid; idx < 1600; idx += 256) {
            int q     = idx >> 4;        // 0..99
            int lowpx = idx & 15;
            int h0 = ty * 2 + (lowpx >> 3);
            int w0 = tx * 8 + (lowpx & 7);
            int px = (h0 << 6) + w0;
            float v = P[((0 * 2 + b) * 128 + q) * 4096 + px]
                    + P[((1 * 2 + b) * 128 + q) * 4096 + px]
                    + P[((2 * 2 + b) * 128 + q) * 4096 + px]
                    + beff[q];
            sm[(q >> 2) * 64 + lowpx * 4 + (q & 3)] = v;
        }
    }
    __syncthreads();
    if (tid < 64) {
        float v[25];
#pragma unroll
        for (int k = 0; k < 25; ++k) v[k] = sm[k * 64 + tid];
        float m = v[0];
#pragma unroll
        for (int k = 1; k < 25; ++k) m = fmaxf(m, v[k]);
        float s = 0.f;
#pragma unroll
        for (int k = 0; k < 25; ++k) { v[k] = __expf(v[k] - m); s += v[k]; }
        float inv = 1.f / s;
#pragma unroll
        for (int k = 0; k < 25; ++k) sm[k * 64 + tid] = v[k] * inv;
    }
    __syncthreads();
    {
        int lowpx = tid & 15;
        int cgrp  = tid >> 4;
        int ly = lowpx >> 3, lx = lowpx & 7;
        float acc[8][4];
#pragma unroll
        for (int cc = 0; cc < 8; ++cc)
#pragma unroll
            for (int s = 0; s < 4; ++s) acc[cc][s] = 0.f;
#pragma unroll
        for (int k = 0; k < 25; ++k) {
            int i = k / 5, j = k % 5;
            float4 wk4 = *(const float4*)&sm[k * 64 + lowpx * 4];
            const float* tb = buf0 + (cgrp * 8) * 73 + (ly + i) * 12 + (lx + j);
#pragma unroll
            for (int cc = 0; cc < 8; ++cc) {
                float tap = tb[cc * 73];
                acc[cc][0] += wk4.x * tap;
                acc[cc][1] += wk4.y * tap;
                acc[cc][2] += wk4.z * tap;
                acc[cc][3] += wk4.w * tap;
            }
        }
        int p0 = (ly * 2) * 16 + lx * 2;
#pragma unroll
        for (int cc = 0; cc < 8; ++cc) {
            int c = cgrp * 8 + cc;
            int sw = RESW(c);
            *(float2*)&re[c * 64 + (p0 ^ sw)]        = make_float2(acc[cc][0], acc[cc][1]);
            *(float2*)&re[c * 64 + ((p0 + 16) ^ sw)] = make_float2(acc[cc][2], acc[cc][3]);
        }
    }
    int og = tid >> 4;
    int pg = tid & 15;
    float accp[8][4];
#pragma unroll
    for (int oo = 0; oo < 8; ++oo)
#pragma unroll
        for (int u = 0; u < 4; ++u) accp[oo][u] = 0.f;
    for (int ch = 0; ch < 2; ++ch) {
        __syncthreads();
        for (int idx = tid; idx < 8192; idx += 256) {
            int o = idx & 127;
            int c = idx >> 7;
            buf0[c * 128 + o] = wproj[(o << 7) + ch * 64 + c];
        }
        __syncthreads();
#pragma unroll 2
        for (int c = 0; c < 64; ++c) {
            int gc = ch * 64 + c;
            float4 rv = *(const float4*)&re[gc * 64 + ((pg * 4) ^ RESW(gc))];
            float4 wa = *(const float4*)&buf0[c * 128 + og * 8];
            float4 wb = *(const float4*)&buf0[c * 128 + og * 8 + 4];
            float wv[8] = {wa.x, wa.y, wa.z, wa.w, wb.x, wb.y, wb.z, wb.w};
            float rvv[4] = {rv.x, rv.y, rv.z, rv.w};
#pragma unroll
            for (int oo = 0; oo < 8; ++oo)
#pragma unroll
                for (int u = 0; u < 4; ++u) accp[oo][u] += wv[oo] * rvv[u];
        }
    }
    int hs  = ty * 4 + (pg >> 2);
    int wsb = tx * 16 + (pg & 3) * 4;
#pragma unroll
    for (int oo = 0; oo < 8; ++oo) {
        int o = og * 8 + oo;
        float bo = bproj[o];
        float4 v = make_float4(accp[oo][0] + bo, accp[oo][1] + bo,
                               accp[oo][2] + bo, accp[oo][3] + bo);
        *(float4*)(out + ((b * OUTC + o) << 14) + (hs << 7) + wsb) = v;
    }
}

extern "C" void kernel_launch(void* const* d_in, const int* in_sizes, int n_in,
                              void* d_out, int out_size, void* d_ws, size_t ws_size,
                              hipStream_t stream) {
    const float* x      = (const float*)d_in[0];
    const float* w_comp = (const float*)d_in[1];
    const float* b_comp = (const float*)d_in[2];
    const float* w_enc  = (const float*)d_in[3];
    const float* b_enc  = (const float*)d_in[4];
    const float* w_proj = (const float*)d_in[5];
    const float* b_proj = (const float*)d_in[6];
    float* out = (float*)d_out;

    // ws layout (≈14.4 MB total)
    unsigned short* xt   = (unsigned short*)d_ws;                                   // 2 MB
    unsigned short* weff = (unsigned short*)((char*)d_ws + (2u << 20));             // 288 KB
    float*          beff = (float*)((char*)d_ws + (2u << 20) + 294912);             // 512 B
    float*          P    = (float*)((char*)d_ws + (2u << 20) + 294912 + 512);       // 12 MB

    k_x2bf<<<256, 128, 0, stream>>>(x, xt);
    k_wfold<<<577, 256, 0, stream>>>(w_enc, w_comp, b_enc, b_comp, weff, beff);
    k_encmfma<<<384, 512, 0, stream>>>(xt, weff, P);
    k_reassemble<<<512, 256, 0, stream>>>(x, P, beff, w_proj, b_proj, out);
}

// Round 4
// 122.706 us; speedup vs baseline: 1.7087x; 1.1638x over previous
//
#include <hip/hip_runtime.h>

constexpr int QQ = 100;

using short8 = __attribute__((ext_vector_type(8))) short;
using f32x4  = __attribute__((ext_vector_type(4))) float;

__device__ inline unsigned short f2bf(float f) {
    unsigned u = __float_as_uint(f);
    return (unsigned short)((u + 0x7FFF + ((u >> 16) & 1)) >> 16);
}
__device__ inline float bf2f(unsigned short us) {
    return __uint_as_float(((unsigned)us) << 16);
}

// ---------------- K0: prep — x->bf16 transpose, weight fold, wproj->bf16 ----------------
// blocks 0..127: x2bf (b,y);  128..703: wfold;  704: beff + wpb
__global__ __launch_bounds__(256)
void k_prep(const float* __restrict__ x, const float* __restrict__ we,
            const float* __restrict__ wc, const float* __restrict__ be,
            const float* __restrict__ bc, const float* __restrict__ wproj,
            unsigned short* __restrict__ xt, unsigned short* __restrict__ weff,
            float* __restrict__ beff, unsigned short* __restrict__ wpb) {
    int blk = blockIdx.x;
    int tid = threadIdx.x;
    if (blk < 128) {
        __shared__ unsigned short t[64 * 136];
        int b = blk >> 6, y = blk & 63;
        int lx = tid & 63, cg = tid >> 6;
        const float* xb = x + (b * 128 + cg * 32) * 4096 + y * 64 + lx;
#pragma unroll 8
        for (int i = 0; i < 32; ++i)
            t[lx * 136 + cg * 32 + i] = f2bf(xb[i * 4096]);
        __syncthreads();
        int px = tid >> 2, ck = tid & 3;
        unsigned short* dst = xt + (b * 4096 + y * 64 + px) * 128 + ck * 32;
        const unsigned short* src = t + px * 136 + ck * 32;
#pragma unroll
        for (int j = 0; j < 4; ++j)
            *(short8*)(dst + j * 8) = *(const short8*)(src + j * 8);
        return;
    }
    if (blk < 704) {
        int gid = (blk - 128) * 256 + tid;   // < 147456 = 128*1152
        int q = gid / 1152;
        int r = gid - q * 1152;
        float acc = 0.f;
        if (q < QQ) {
            const float* wep = we + q * 576 + (r >> 7);
            const float* wcp = wc + (r & 127);
#pragma unroll 8
            for (int m = 0; m < 64; ++m)
                acc += wep[m * 9] * wcp[m * 128];
        }
        weff[gid] = f2bf(acc);
        return;
    }
    if (tid < 128) {
        float s = 0.f;
        if (tid < QQ) {
            s = be[tid];
            for (int m = 0; m < 64; ++m) {
                float t2 = 0.f;
#pragma unroll
                for (int k = 0; k < 9; ++k) t2 += we[(tid * 64 + m) * 9 + k];
                s += t2 * bc[m];
            }
        }
        beff[tid] = s;
    }
    for (int i = tid; i < 16384; i += 256)
        wpb[i] = f2bf(wproj[i]);
}

// ---------------- K1: encoder MFMA, A in registers, ONE barrier ----------------
// grid = 3 ks x 2 b x 64 tiles(8x8 px) = 384 blocks, 256 thr (4 waves).
// P[ks][b][q<100][4096] f32 partials.
__global__ __launch_bounds__(256)
void k_enc(const unsigned short* __restrict__ xt, const unsigned short* __restrict__ weff,
           float* __restrict__ P) {
    __shared__ unsigned short xhs[100 * 136];   // 10x10 px halo x 128c
    int blk = blockIdx.x;
    int ks = blk >> 7;
    int rem = blk & 127;
    int b = rem >> 6;
    int tile = rem & 63;
    int y0 = (tile >> 3) * 8, x0 = (tile & 7) * 8;
    int tid = threadIdx.x;
    int lane = tid & 63, w = tid >> 6;
    int l15 = lane & 15, kgrp = lane >> 4;

    // A-fragments in registers: 3 kappa x 4 c-steps x 2 m-frags
    short8 afr[3][4][2];
#pragma unroll
    for (int kk = 0; kk < 3; ++kk)
#pragma unroll
        for (int cs = 0; cs < 4; ++cs)
#pragma unroll
            for (int mf = 0; mf < 2; ++mf) {
                int q = (w * 2 + mf) * 16 + l15;
                afr[kk][cs][mf] = *(const short8*)(weff + (q * 9 + ks * 3 + kk) * 128
                                                   + cs * 32 + kgrp * 8);
            }

    // stage halo (zeros outside)
    for (int idx = tid; idx < 800; idx += 256) {
        int hp = idx >> 3, cq = idx & 7;
        int hy = hp / 10, hx = hp - hy * 10;
        int gy = y0 - 1 + hy, gx = x0 - 1 + hx;
        short8 v0 = {0,0,0,0,0,0,0,0}, v1 = {0,0,0,0,0,0,0,0};
        if ((unsigned)gy < 64u && (unsigned)gx < 64u) {
            const unsigned short* src = xt + (b * 4096 + gy * 64 + gx) * 128 + cq * 16;
            v0 = *(const short8*)src;
            v1 = *(const short8*)(src + 8);
        }
        *(short8*)&xhs[hp * 136 + cq * 16] = v0;
        *(short8*)&xhs[hp * 136 + cq * 16 + 8] = v1;
    }
    __syncthreads();

    int px = 0;
    f32x4 acc[2][4];
#pragma unroll
    for (int mf = 0; mf < 2; ++mf)
#pragma unroll
        for (int nf = 0; nf < 4; ++nf) acc[mf][nf] = f32x4{0.f, 0.f, 0.f, 0.f};

#pragma unroll
    for (int kk = 0; kk < 3; ++kk) {
        int kap = ks * 3 + kk;
        int dy = kap / 3, dx = kap % 3;
#pragma unroll
        for (int nf = 0; nf < 4; ++nf) {
            px = nf * 16 + l15;
            int py = px >> 3, pxx = px & 7;
            int hp = (py + dy) * 10 + (pxx + dx);
#pragma unroll
            for (int cs = 0; cs < 4; ++cs) {
                short8 bfrag = *(const short8*)&xhs[hp * 136 + cs * 32 + kgrp * 8];
#pragma unroll
                for (int mf = 0; mf < 2; ++mf)
                    acc[mf][nf] = __builtin_amdgcn_mfma_f32_16x16x32_bf16(
                        afr[kk][cs][mf], bfrag, acc[mf][nf], 0, 0, 0);
            }
        }
    }
    float* Pb = P + (ks * 2 + b) * QQ * 4096;
#pragma unroll
    for (int mf = 0; mf < 2; ++mf)
#pragma unroll
        for (int nf = 0; nf < 4; ++nf) {
            px = nf * 16 + l15;
            int py = px >> 3, pxx = px & 7;
            int gpx = (y0 + py) * 64 + (x0 + pxx);
            int qb = (w * 2 + mf) * 16 + kgrp * 4;
#pragma unroll
            for (int r = 0; r < 4; ++r)
                if (qb + r < QQ) Pb[(qb + r) * 4096 + gpx] = acc[mf][nf][r];
        }
}

// ---------------- K2: softmax + 25-tap reassembly -> re bf16 [b][p][c] ----------------
// grid = 2 b x 32 ty x 8 tx = 512 blocks; tile = 4 hs x 16 ws = 64 out px.
__global__ __launch_bounds__(256)
void k_re(const unsigned short* __restrict__ xt, const float* __restrict__ P,
          const float* __restrict__ beff, unsigned short* __restrict__ re) {
    __shared__ unsigned short xs[72 * 136];   // 6x12 lowres halo x 128c
    __shared__ float sm[1600];                // [25 k][64 e], e = lowpx*4+subpx
    int bid = blockIdx.x;
    int b = bid >> 8;
    int rem = bid & 255;
    int ty = rem >> 3, tx = rem & 7;
    int tid = threadIdx.x;

    int R0 = ty * 2 - 2, C0 = tx * 8 - 2;
    for (int idx = tid; idx < 576; idx += 256) {
        int hp = idx >> 3, cq = idx & 7;
        int hy = hp / 12, hx = hp - hy * 12;
        int gr = R0 + hy, gc = C0 + hx;
        short8 v0 = {0,0,0,0,0,0,0,0}, v1 = {0,0,0,0,0,0,0,0};
        if ((unsigned)gr < 64u && (unsigned)gc < 64u) {
            const unsigned short* src = xt + (b * 4096 + gr * 64 + gc) * 128 + cq * 16;
            v0 = *(const short8*)src;
            v1 = *(const short8*)(src + 8);
        }
        *(short8*)&xs[hp * 136 + cq * 16] = v0;
        *(short8*)&xs[hp * 136 + cq * 16 + 8] = v1;
    }
    for (int idx = tid; idx < 1600; idx += 256) {
        int q = idx >> 4, lowpx = idx & 15;
        int h0 = ty * 2 + (lowpx >> 3), w0 = tx * 8 + (lowpx & 7);
        int px = (h0 << 6) + w0;
        float v = P[(b * QQ + q) * 4096 + px]
                + P[((2 + b) * QQ + q) * 4096 + px]
                + P[((4 + b) * QQ + q) * 4096 + px] + beff[q];
        sm[(q >> 2) * 64 + lowpx * 4 + (q & 3)] = v;
    }
    __syncthreads();
    // wave-parallel softmax: thread -> (entry e, k-group kg); 4-lane shfl reduce
    {
        int e = tid >> 2, kg = tid & 3;
        float v[7];
        float m = -1e30f;
#pragma unroll
        for (int j = 0; j < 7; ++j) {
            int k = kg + 4 * j;
            float val = (k < 25) ? sm[k * 64 + e] : -1e30f;
            v[j] = val; m = fmaxf(m, val);
        }
        m = fmaxf(m, __shfl_xor(m, 1));
        m = fmaxf(m, __shfl_xor(m, 2));
        float s = 0.f;
#pragma unroll
        for (int j = 0; j < 7; ++j) {
            int k = kg + 4 * j;
            if (k < 25) { v[j] = __expf(v[j] - m); s += v[j]; }
        }
        s += __shfl_xor(s, 1);
        s += __shfl_xor(s, 2);
        float inv = 1.f / s;
#pragma unroll
        for (int j = 0; j < 7; ++j) {
            int k = kg + 4 * j;
            if (k < 25) sm[k * 64 + e] = v[j] * inv;
        }
    }
    __syncthreads();
    // reassembly: thread = (lowpx, 8-channel group); 4 subpx share taps
    int lowpx = tid & 15, cgrp = tid >> 4;
    int ly = lowpx >> 3, lx = lowpx & 7;
    float acc[8][4];
#pragma unroll
    for (int cc = 0; cc < 8; ++cc)
#pragma unroll
        for (int s = 0; s < 4; ++s) acc[cc][s] = 0.f;
#pragma unroll
    for (int k = 0; k < 25; ++k) {
        int i = k / 5, j = k % 5;
        float4 wk4 = *(const float4*)&sm[k * 64 + lowpx * 4];
        short8 tap8 = *(const short8*)&xs[((ly + i) * 12 + (lx + j)) * 136 + cgrp * 8];
#pragma unroll
        for (int cc = 0; cc < 8; ++cc) {
            float tap = bf2f((unsigned short)tap8[cc]);
            acc[cc][0] += wk4.x * tap;
            acc[cc][1] += wk4.y * tap;
            acc[cc][2] += wk4.z * tap;
            acc[cc][3] += wk4.w * tap;
        }
    }
    int hb = ty * 4 + ly * 2, wb = tx * 16 + lx * 2;
#pragma unroll
    for (int s = 0; s < 4; ++s) {
        int hs = hb + (s >> 1), ws = wb + (s & 1);
        short8 pk;
#pragma unroll
        for (int cc = 0; cc < 8; ++cc) pk[cc] = (short)f2bf(acc[cc][s]);
        *(short8*)(re + (b * 16384 + hs * 128 + ws) * 128 + cgrp * 8) = pk;
    }
}

// ---------------- K3: projection MFMA GEMM 128o x 64px x 128c ----------------
// grid = 2 b x 256 px-tiles = 512 blocks, 256 thr (4 waves, 1 n-frag each).
__global__ __launch_bounds__(256)
void k_proj(const unsigned short* __restrict__ re, const unsigned short* __restrict__ wpb,
            const float* __restrict__ bproj, float* __restrict__ out) {
    __shared__ unsigned short At[128 * 136];
    __shared__ unsigned short Bt[64 * 136];
    __shared__ float bs[128];
    int blk = blockIdx.x;
    int b = blk >> 8;
    int pbase = (blk & 255) * 64;
    int tid = threadIdx.x;
    for (int idx = tid; idx < 1024; idx += 256) {
        int o = idx >> 3, cq = idx & 7;
        const unsigned short* s = wpb + o * 128 + cq * 16;
        *(short8*)&At[o * 136 + cq * 16]     = *(const short8*)s;
        *(short8*)&At[o * 136 + cq * 16 + 8] = *(const short8*)(s + 8);
    }
    for (int idx = tid; idx < 512; idx += 256) {
        int p = idx >> 3, cq = idx & 7;
        const unsigned short* s = re + (b * 16384 + pbase + p) * 128 + cq * 16;
        *(short8*)&Bt[p * 136 + cq * 16]     = *(const short8*)s;
        *(short8*)&Bt[p * 136 + cq * 16 + 8] = *(const short8*)(s + 8);
    }
    if (tid < 128) bs[tid] = bproj[tid];
    __syncthreads();
    int lane = tid & 63, w = tid >> 6;
    int l15 = lane & 15, kgrp = lane >> 4;
    f32x4 acc[8];
#pragma unroll
    for (int mf = 0; mf < 8; ++mf) acc[mf] = f32x4{0.f, 0.f, 0.f, 0.f};
#pragma unroll
    for (int cs = 0; cs < 4; ++cs) {
        short8 bfrag = *(const short8*)&Bt[(w * 16 + l15) * 136 + cs * 32 + kgrp * 8];
#pragma unroll
        for (int mf = 0; mf < 8; ++mf) {
            short8 af = *(const short8*)&At[(mf * 16 + l15) * 136 + cs * 32 + kgrp * 8];
            acc[mf] = __builtin_amdgcn_mfma_f32_16x16x32_bf16(af, bfrag, acc[mf], 0, 0, 0);
        }
    }
    int p = pbase + w * 16 + l15;
    float* ob = out + (b * 128) * 16384 + p;
#pragma unroll
    for (int mf = 0; mf < 8; ++mf) {
        int qb = mf * 16 + kgrp * 4;
#pragma unroll
        for (int r = 0; r < 4; ++r)
            ob[(qb + r) * 16384] = acc[mf][r] + bs[qb + r], ob += 0;
    }
}

extern "C" void kernel_launch(void* const* d_in, const int* in_sizes, int n_in,
                              void* d_out, int out_size, void* d_ws, size_t ws_size,
                              hipStream_t stream) {
    const float* x      = (const float*)d_in[0];
    const float* w_comp = (const float*)d_in[1];
    const float* b_comp = (const float*)d_in[2];
    const float* w_enc  = (const float*)d_in[3];
    const float* b_enc  = (const float*)d_in[4];
    const float* w_proj = (const float*)d_in[5];
    const float* b_proj = (const float*)d_in[6];
    float* out = (float*)d_out;

    // ws layout (bytes), all 256-aligned; total ~20.6 MB
    char* base = (char*)d_ws;
    unsigned short* xt   = (unsigned short*)(base);                 // 2,097,152
    unsigned short* weff = (unsigned short*)(base + 2097152);       //   294,912
    float*          beff = (float*)         (base + 2392064);       //       512
    unsigned short* wpb  = (unsigned short*)(base + 2392576);       //    32,768
    float*          P    = (float*)         (base + 2425344);       // 9,830,400 (6*100*4096*4)
    unsigned short* re   = (unsigned short*)(base + 12255744);      // 8,388,608

    k_prep<<<705, 256, 0, stream>>>(x, w_enc, w_comp, b_enc, b_comp, w_proj,
                                    xt, weff, beff, wpb);
    k_enc<<<384, 256, 0, stream>>>(xt, weff, P);
    k_re<<<512, 256, 0, stream>>>(xt, P, beff, re);
    k_proj<<<512, 256, 0, stream>>>(re, wpb, b_proj, out);
}

// Round 5
// 106.793 us; speedup vs baseline: 1.9633x; 1.1490x over previous
//
#include <hip/hip_runtime.h>

constexpr int QQ = 100;

using short8 = __attribute__((ext_vector_type(8))) short;
using f32x4  = __attribute__((ext_vector_type(4))) float;

__device__ inline unsigned short f2bf(float f) {
    unsigned u = __float_as_uint(f);
    return (unsigned short)((u + 0x7FFF + ((u >> 16) & 1)) >> 16);
}
__device__ inline float bf2f(unsigned short us) {
    return __uint_as_float(((unsigned)us) << 16);
}

// ---------------- K0: prep ----------------
// blocks 0..511: x -> xt (bf16, [b][px][c]); 512..623: weight fold -> weffR
// (fragment-major); 624: beff + wproj -> wpbR (fragment-major)
__global__ __launch_bounds__(256)
void k_prep(const float* __restrict__ x, const float* __restrict__ we,
            const float* __restrict__ wc, const float* __restrict__ be,
            const float* __restrict__ bc, const float* __restrict__ wproj,
            unsigned short* __restrict__ xt, unsigned short* __restrict__ weffR,
            float* __restrict__ beff, unsigned short* __restrict__ wpbR) {
    __shared__ float smf[2880];   // 11.5 KB; x2bf path uses it as shorts
    int blk = blockIdx.x, tid = threadIdx.x;
    if (blk < 512) {
        unsigned short* t = (unsigned short*)smf;   // [64 px][pitch 40] shorts
        int b = blk >> 8, y = (blk >> 2) & 63, cq = blk & 3;
        int lx = tid & 63, cg = tid >> 6;
        const float* xb = x + (b * 128 + cq * 32 + cg * 8) * 4096 + y * 64 + lx;
#pragma unroll
        for (int i = 0; i < 8; ++i)
            t[lx * 40 + cg * 8 + i] = f2bf(xb[i * 4096]);
        __syncthreads();
        int px = tid >> 2, j = tid & 3;
        *(short8*)(xt + (b * 4096 + y * 64 + px) * 128 + cq * 32 + j * 8)
            = *(const short8*)(t + px * 40 + j * 8);
        return;
    }
    if (blk < 624) {
        int q = blk - 512;            // 0..111 (>=100: zero-fill)
        float* we_s = smf;            // 576
        float* red  = smf + 576;      // 18*128
        if (q < QQ) {
            for (int idx = tid; idx < 576; idx += 256) we_s[idx] = we[q * 576 + idx];
            __syncthreads();
            int c = tid & 127, mh = tid >> 7;
            float acc[9];
#pragma unroll
            for (int k = 0; k < 9; ++k) acc[k] = 0.f;
            for (int m = 0; m < 32; ++m) {
                int mm = mh * 32 + m;
                float wv = wc[mm * 128 + c];
#pragma unroll
                for (int k = 0; k < 9; ++k) acc[k] += we_s[mm * 9 + k] * wv;
            }
#pragma unroll
            for (int k = 0; k < 9; ++k) red[(mh * 9 + k) * 128 + c] = acc[k];
            __syncthreads();
        }
        int mf = q >> 4, l15 = q & 15;
        for (int idx = tid; idx < 1152; idx += 256) {
            int kap = idx >> 7, r = idx & 127;
            float v = (q < QQ) ? (red[kap * 128 + r] + red[(9 + kap) * 128 + r]) : 0.f;
            int c32 = r >> 5, kgrp = (r >> 3) & 3, j = r & 7;
            weffR[(((kap * 4 + c32) * 7 + mf) * 64 + kgrp * 16 + l15) * 8 + j] = f2bf(v);
        }
        return;
    }
    // blk == 624: beff + wpbR
    if (tid < 128) {
        float s = 0.f;
        if (tid < QQ) {
            s = be[tid];
            for (int m = 0; m < 64; ++m) {
                float t2 = 0.f;
#pragma unroll
                for (int k = 0; k < 9; ++k) t2 += we[(tid * 64 + m) * 9 + k];
                s += t2 * bc[m];
            }
        }
        beff[tid] = s;
    }
    for (int idx = tid; idx < 16384; idx += 256) {
        int o = idx >> 7, c = idx & 127;
        int cs = c >> 5, kgrp = (c >> 3) & 3, j = c & 7;
        int mf = o >> 4, l15 = o & 15;
        wpbR[((cs * 8 + mf) * 64 + kgrp * 16 + l15) * 8 + j] = f2bf(wproj[idx]);
    }
}

// ---------------- K1: fully fused enc + softmax + reassembly + projection ----------------
// grid = 2 b x 32 ty x 8 tx = 512 blocks (2/CU, whole grid resident), 256 thr.
__global__ __launch_bounds__(256)
void k_main(const unsigned short* __restrict__ xt, const unsigned short* __restrict__ weffR,
            const float* __restrict__ beff, const unsigned short* __restrict__ wpbR,
            const float* __restrict__ bproj, float* __restrict__ out) {
    __shared__ __align__(16) char smem[56448];
    unsigned short* xs = (unsigned short*)smem;            // [72 px][136] shorts, 19584 B
    float* sm          = (float*)(smem + 19584);           // [25 k][64 e], 6400 B
    float* psum        = (float*)(smem + 25984);           // [4 w][112 q][17], 30464 B
    unsigned short* re = (unsigned short*)(smem + 25984);  // [64 p][136] shorts (aliases psum)

    int bid = blockIdx.x;
    int b = bid >> 8, rem = bid & 255;
    int ty = rem >> 3, tx = rem & 7;
    int tid = threadIdx.x;
    int lane = tid & 63, w = tid >> 6;
    int l15 = lane & 15, kgrp = lane >> 4;

    // ---- phase 1: stage 6x12 low-res halo x 128c (serves BOTH enc conv and reassembly)
    int R0 = ty * 2 - 2, C0 = tx * 8 - 2;
    for (int idx = tid; idx < 576; idx += 256) {
        int hp = idx >> 3, cq = idx & 7;
        int hy = hp / 12, hx = hp - hy * 12;
        int gr = R0 + hy, gc = C0 + hx;
        short8 v0 = {0,0,0,0,0,0,0,0}, v1 = {0,0,0,0,0,0,0,0};
        if ((unsigned)gr < 64u && (unsigned)gc < 64u) {
            const unsigned short* src = xt + (b * 4096 + gr * 64 + gc) * 128 + cq * 16;
            v0 = *(const short8*)src;
            v1 = *(const short8*)(src + 8);
        }
        *(short8*)&xs[hp * 136 + cq * 16]     = v0;
        *(short8*)&xs[hp * 136 + cq * 16 + 8] = v1;
    }
    __syncthreads();

    // ---- phase 2: encoder GEMM (M=112 q, N=16 lowpx, K=1152); wave w owns c-quarter w
    int ly = l15 >> 3, lx = l15 & 7;
    f32x4 acc[7];
#pragma unroll
    for (int mf = 0; mf < 7; ++mf) acc[mf] = f32x4{0.f, 0.f, 0.f, 0.f};
#pragma unroll
    for (int kap = 0; kap < 9; ++kap) {
        int dy = kap / 3, dx = kap % 3;
        short8 bfrag = *(const short8*)&xs[((ly + dy + 1) * 12 + lx + dx + 1) * 136
                                           + w * 32 + kgrp * 8];
        const unsigned short* wrk = weffR + ((kap * 4 + w) * 7) * 512 + lane * 8;
#pragma unroll
        for (int mf = 0; mf < 7; ++mf) {
            short8 af = *(const short8*)(wrk + mf * 512);
            acc[mf] = __builtin_amdgcn_mfma_f32_16x16x32_bf16(af, bfrag, acc[mf], 0, 0, 0);
        }
    }
    // ---- phase 3: per-wave partials to LDS
#pragma unroll
    for (int mf = 0; mf < 7; ++mf)
#pragma unroll
        for (int r = 0; r < 4; ++r) {
            int q = mf * 16 + kgrp * 4 + r;
            psum[(w * 112 + q) * 17 + l15] = acc[mf][r];
        }
    __syncthreads();

    // ---- phase 4: reduce 4 waves + bias -> sm[(q>>2)*64 + lowpx*4 + (q&3)]
    for (int idx = tid; idx < 1600; idx += 256) {
        int q = idx >> 4, lowpx = idx & 15;
        float v = psum[q * 17 + lowpx] + psum[(112 + q) * 17 + lowpx]
                + psum[(224 + q) * 17 + lowpx] + psum[(336 + q) * 17 + lowpx] + beff[q];
        sm[(q >> 2) * 64 + lowpx * 4 + (q & 3)] = v;
    }
    __syncthreads();

    // ---- phase 5: wave-parallel softmax over 25 k
    {
        int e = tid >> 2, kg = tid & 3;
        float v[7];
        float m = -1e30f;
#pragma unroll
        for (int j = 0; j < 7; ++j) {
            int k = kg + 4 * j;
            float val = (k < 25) ? sm[k * 64 + e] : -1e30f;
            v[j] = val; m = fmaxf(m, val);
        }
        m = fmaxf(m, __shfl_xor(m, 1));
        m = fmaxf(m, __shfl_xor(m, 2));
        float s = 0.f;
#pragma unroll
        for (int j = 0; j < 7; ++j) {
            int k = kg + 4 * j;
            if (k < 25) { v[j] = __expf(v[j] - m); s += v[j]; }
        }
        s += __shfl_xor(s, 1);
        s += __shfl_xor(s, 2);
        float inv = 1.f / s;
#pragma unroll
        for (int j = 0; j < 7; ++j) {
            int k = kg + 4 * j;
            if (k < 25) sm[k * 64 + e] = v[j] * inv;
        }
    }
    __syncthreads();

    // ---- phase 6: reassembly -> re (LDS, aliases dead psum)
    {
        int lowpx = tid & 15, cgrp = tid >> 4;
        int ly2 = lowpx >> 3, lx2 = lowpx & 7;
        float racc[8][4];
#pragma unroll
        for (int cc = 0; cc < 8; ++cc)
#pragma unroll
            for (int s = 0; s < 4; ++s) racc[cc][s] = 0.f;
#pragma unroll
        for (int k = 0; k < 25; ++k) {
            int i = k / 5, j = k % 5;
            float4 wk4 = *(const float4*)&sm[k * 64 + lowpx * 4];
            short8 tap8 = *(const short8*)&xs[((ly2 + i) * 12 + (lx2 + j)) * 136 + cgrp * 8];
#pragma unroll
            for (int cc = 0; cc < 8; ++cc) {
                float tap = bf2f((unsigned short)tap8[cc]);
                racc[cc][0] += wk4.x * tap;
                racc[cc][1] += wk4.y * tap;
                racc[cc][2] += wk4.z * tap;
                racc[cc][3] += wk4.w * tap;
            }
        }
#pragma unroll
        for (int s = 0; s < 4; ++s) {
            int p = (ly2 * 2 + (s >> 1)) * 16 + lx2 * 2 + (s & 1);
            short8 pk;
#pragma unroll
            for (int cc = 0; cc < 8; ++cc) pk[cc] = (short)f2bf(racc[cc][s]);
            *(short8*)&re[p * 136 + cgrp * 8] = pk;
        }
    }
    __syncthreads();

    // ---- phase 7: projection GEMM (M=128 o, N=64 p, K=128 c); wave w owns n-frag w
    f32x4 pacc[8];
#pragma unroll
    for (int mf = 0; mf < 8; ++mf) pacc[mf] = f32x4{0.f, 0.f, 0.f, 0.f};
#pragma unroll
    for (int cs = 0; cs < 4; ++cs) {
        short8 bfrag = *(const short8*)&re[(w * 16 + l15) * 136 + cs * 32 + kgrp * 8];
        const unsigned short* wrp = wpbR + (cs * 8) * 512 + lane * 8;
#pragma unroll
        for (int mf = 0; mf < 8; ++mf) {
            short8 af = *(const short8*)(wrp + mf * 512);
            pacc[mf] = __builtin_amdgcn_mfma_f32_16x16x32_bf16(af, bfrag, pacc[mf], 0, 0, 0);
        }
    }
    // ---- phase 8: store (16 consecutive ws per quarter-wave)
    int hs = ty * 4 + w, ws = tx * 16 + l15;
    float* ob = out + (b * 128) * 16384 + hs * 128 + ws;
#pragma unroll
    for (int mf = 0; mf < 8; ++mf)
#pragma unroll
        for (int r = 0; r < 4; ++r) {
            int o = mf * 16 + kgrp * 4 + r;
            ob[o * 16384] = pacc[mf][r] + bproj[o];
        }
}

extern "C" void kernel_launch(void* const* d_in, const int* in_sizes, int n_in,
                              void* d_out, int out_size, void* d_ws, size_t ws_size,
                              hipStream_t stream) {
    const float* x      = (const float*)d_in[0];
    const float* w_comp = (const float*)d_in[1];
    const float* b_comp = (const float*)d_in[2];
    const float* w_enc  = (const float*)d_in[3];
    const float* b_enc  = (const float*)d_in[4];
    const float* w_proj = (const float*)d_in[5];
    const float* b_proj = (const float*)d_in[6];
    float* out = (float*)d_out;

    char* base = (char*)d_ws;
    unsigned short* xt    = (unsigned short*)(base);              // 2,097,152 B
    unsigned short* weffR = (unsigned short*)(base + 2097152);    //   258,048 B (252*512*2)
    float*          beff  = (float*)         (base + 2355200);    //       512 B
    unsigned short* wpbR  = (unsigned short*)(base + 2355712);    //    32,768 B

    k_prep<<<625, 256, 0, stream>>>(x, w_enc, w_comp, b_enc, b_comp, w_proj,
                                    xt, weffR, beff, wpbR);
    k_main<<<512, 256, 0, stream>>>(xt, weffR, beff, wpbR, b_proj, out);
}